// Round 4
// baseline (1541.771 us; speedup 1.0000x reference)
//
#include <hip/hip_runtime.h>
#include <hip/hip_bf16.h>
#include <hip/hip_cooperative_groups.h>

namespace cg = cooperative_groups;

// Problem constants (from reference)
#define IN_PER_SIDE   40960
#define IN_TOTAL      81920     // 2 * 40960
#define L1            512
#define L2            32
#define L3_           32
#define BATCH         4096
#define MAXIDX        128       // per-row index capacity (~60 used)

// clang-native vectors (HIP float4 is a class; builtins reject it)
typedef float        v4f __attribute__((ext_vector_type(4)));
typedef float        v8f __attribute__((ext_vector_type(8)));
typedef _Float16     v4h __attribute__((ext_vector_type(4)));
typedef _Float16     v8h __attribute__((ext_vector_type(8)));
typedef unsigned int v4u __attribute__((ext_vector_type(4)));

// ws layout:
//   [0, WT_BYTES)          : WTh fp16 transposed W_in [81920][512]  (83.9 MB)
//   [CNT_OFF, +16 KB)      : cnt, per-row active count
//   [IDX_OFF, +2 MB)       : idxg, per-row compact feature lists
#define WT_BYTES ((size_t)IN_TOTAL * L1 * sizeof(_Float16))
#define CNT_OFF  WT_BYTES
#define IDX_OFF  (WT_BYTES + 16384)
#define WS_NEED  (IDX_OFF + (size_t)BATCH * MAXIDX * 4)

// ===========================================================================
// Cooperative mega-kernel: transpose + scan (phase A), grid sync, gather+MLP
// (phase B). Rationale: across rounds 0-3, instruction-level scan tweaks were
// all null -> the ~3.4 TB/s scan is phase-structural (blocks lockstep through
// scan -> gather -> MLP, starving HBM during non-scan phases; transpose
// dispatch serialized in front). Phase A here is one homogeneous 1.68 GB
// stream over all blocks; phase B is the latency-bound tail, once.
// Scan output goes through ws as compact per-row lists written with coalesced
// bursts — NO global atomics (round-2's mistake).
// ===========================================================================
__global__ __launch_bounds__(512) void nnue_mega(
    const float* __restrict__ W, _Float16* __restrict__ WTh,
    const float* __restrict__ wf, const float* __restrict__ bfeat,
    int* __restrict__ cnt, int* __restrict__ idxg,
    const float* __restrict__ b_in,
    const float* __restrict__ W1, const float* __restrict__ b1,
    const float* __restrict__ W2, const float* __restrict__ b2,
    const float* __restrict__ W3, const float* __restrict__ b3,
    float* __restrict__ out)
{
    const int t = threadIdx.x;
    const int G = gridDim.x;

    // tile (16.6 KB, phase A) and accs (18 KB, phase B) share one buffer
    __shared__ __align__(16) char smem[8 * 64 * 9 * 4];
    float (*tile)[65] = reinterpret_cast<float (*)[65]>(smem);
    float* accs = reinterpret_cast<float*>(smem);
    __shared__ int   sidx[MAXIDX];
    __shared__ int   scnt;
    __shared__ float l1s[L1];
    __shared__ float l2acc[L2];
    __shared__ float l2s[L2];
    __shared__ float l3s[L3_];

    // ---- Phase A1: transpose share (grid-stride over 10240 64x64 tiles) ----
    for (int tid = blockIdx.x; tid < 1280 * 8; tid += G) {
        const int jt = (tid % 1280) * 64;     // input-feature tile base
        const int ot = (tid / 1280) * 64;     // output-neuron tile base
        {
            const int tx = t & 15;            // float4 column
            const int ty = t >> 4;            // 0..31
#pragma unroll
            for (int k = 0; k < 2; ++k) {
                const int o = ty + 32 * k;
                const v4f* p = (const v4f*)&W[(size_t)(ot + o) * IN_TOTAL + jt + 4 * tx];
                v4f v = __builtin_nontemporal_load(p);
                tile[4 * tx + 0][o] = v.x;
                tile[4 * tx + 1][o] = v.y;
                tile[4 * tx + 2][o] = v.z;
                tile[4 * tx + 3][o] = v.w;
            }
        }
        __syncthreads();
        {
            const int tx = t & 7;             // v8h column (16 B)
            const int ty = t >> 3;            // 0..63 = feature row in tile
            v8f v;
#pragma unroll
            for (int c = 0; c < 8; ++c) v[c] = tile[ty][8 * tx + c];
            v8h h = __builtin_convertvector(v, v8h);
            *(v8h*)&WTh[(size_t)(jt + ty) * L1 + ot + 8 * tx] = h;
        }
        __syncthreads();
    }

    // ---- Phase A2: scan share (grid-stride over batch rows) ----------------
    for (int row = blockIdx.x; row < BATCH; row += G) {
        if (t == 0) scnt = 0;
        __syncthreads();
        const v4u* wrow = (const v4u*)(wf    + (size_t)row * IN_PER_SIDE);
        const v4u* brow = (const v4u*)(bfeat + (size_t)row * IN_PER_SIDE);
        for (int i = t; i < IN_PER_SIDE / 4; i += 512) {
            v4u a = __builtin_nontemporal_load(wrow + i);
            v4u c = __builtin_nontemporal_load(brow + i);
            if (a.x | a.y | a.z | a.w) {
                if (a.x) { int p = atomicAdd(&scnt, 1); if (p < MAXIDX) sidx[p] = 4 * i + 0; }
                if (a.y) { int p = atomicAdd(&scnt, 1); if (p < MAXIDX) sidx[p] = 4 * i + 1; }
                if (a.z) { int p = atomicAdd(&scnt, 1); if (p < MAXIDX) sidx[p] = 4 * i + 2; }
                if (a.w) { int p = atomicAdd(&scnt, 1); if (p < MAXIDX) sidx[p] = 4 * i + 3; }
            }
            if (c.x | c.y | c.z | c.w) {
                if (c.x) { int p = atomicAdd(&scnt, 1); if (p < MAXIDX) sidx[p] = IN_PER_SIDE + 4 * i + 0; }
                if (c.y) { int p = atomicAdd(&scnt, 1); if (p < MAXIDX) sidx[p] = IN_PER_SIDE + 4 * i + 1; }
                if (c.z) { int p = atomicAdd(&scnt, 1); if (p < MAXIDX) sidx[p] = IN_PER_SIDE + 4 * i + 2; }
                if (c.w) { int p = atomicAdd(&scnt, 1); if (p < MAXIDX) sidx[p] = IN_PER_SIDE + 4 * i + 3; }
            }
        }
        __syncthreads();
        const int nn = min(scnt, MAXIDX);
        if (t < nn) idxg[(size_t)row * MAXIDX + t] = sidx[t];   // coalesced burst
        if (t == 0) cnt[row] = nn;
        __syncthreads();
    }

    __threadfence();          // publish WTh / cnt / idxg device-wide
    cg::this_grid().sync();

    // ---- Phase B: gather + MLP (grid-stride over batch rows) ---------------
    const int w = t >> 6;          // wave 0..7
    const int l = t & 63;          // lane 0..63
    const v8h* WTH8 = (const v8h*)WTh;   // feature f -> WTH8[f*64 + l]

    for (int row = blockIdx.x; row < BATCH; row += G) {
        const int n = cnt[row];
        if (t < MAXIDX) {
            const int g = idxg[(size_t)row * MAXIDX + t];
            sidx[t] = (t < n) ? g : 0;       // OOB slots -> valid feature 0
        }
        __syncthreads();

        v8f acc0 = {0, 0, 0, 0, 0, 0, 0, 0};
        v8f acc1 = {0, 0, 0, 0, 0, 0, 0, 0};
        const int J     = (n + 7) >> 3;
        const int Jeven = (J + 1) & ~1;
        {
            const int f0 = w, f1 = w + 8;
            v8h h0 = WTH8[(size_t)sidx[f0 < n ? f0 : 0] * 64 + l];
            float s0 = (f0 < n) ? 1.0f : 0.0f;
            v8h h1 = WTH8[(size_t)sidx[f1 < n ? f1 : 0] * 64 + l];
            float s1 = (f1 < n) ? 1.0f : 0.0f;
            for (int j = 2; j < Jeven; j += 2) {
                const int g0 = w + 8 * j, g1 = g0 + 8;
                v8h p0 = WTH8[(size_t)sidx[g0 < n ? g0 : 0] * 64 + l];
                const float u0 = (g0 < n) ? 1.0f : 0.0f;
                v8h p1 = WTH8[(size_t)sidx[g1 < n ? g1 : 0] * 64 + l];
                const float u1 = (g1 < n) ? 1.0f : 0.0f;
                acc0 += s0 * __builtin_convertvector(h0, v8f);
                acc1 += s1 * __builtin_convertvector(h1, v8f);
                h0 = p0; s0 = u0; h1 = p1; s1 = u1;
            }
            acc0 += s0 * __builtin_convertvector(h0, v8f);
            acc1 += s1 * __builtin_convertvector(h1, v8f);
        }
        acc0 += acc1;

        // pad-9 stride: bank = (9*l + i) % 32, 9 odd -> conflict-free
        {
            float* dst = &accs[(w * 64 + l) * 9];
#pragma unroll
            for (int i = 0; i < 8; ++i) dst[i] = acc0[i];
        }
        __syncthreads();

        {   // reduce waves + bias + clipped ReLU; thread t = neuron t
            const int ll = t >> 3, c = t & 7;
            float s = 0.0f;
#pragma unroll
            for (int ww = 0; ww < 8; ++ww) s += accs[(ww * 64 + ll) * 9 + c];
            l1s[t] = fminf(fmaxf(s + b_in[t], 0.0f), 1.0f);
        }
        __syncthreads();

        {   // l2 = clip(l1 @ W1.T + b1): output k owned by 16 lanes
            const int kk = t >> 4;
            const int gg = t & 15;
            const float* wp = W1 + (size_t)kk * L1;
            float p = 0.0f;
            for (int o = gg; o < L1; o += 16) p += wp[o] * l1s[o];
#pragma unroll
            for (int off = 8; off > 0; off >>= 1) p += __shfl_down(p, off, 16);
            if (gg == 0) l2acc[kk] = p;
        }
        __syncthreads();
        if (t < L2) l2s[t] = fminf(fmaxf(l2acc[t] + b1[t], 0.0f), 1.0f);
        __syncthreads();

        if (t < L3_) {   // l3 = clip(l2 @ W2.T + b2), 32x32
            const float* wp = W2 + (size_t)t * L2;
            float p = b2[t];
#pragma unroll
            for (int q = 0; q < L2; ++q) p += wp[q] * l2s[q];
            l3s[t] = fminf(fmaxf(p, 0.0f), 1.0f);
        }
        __syncthreads();

        if (t == 0) {    // out = l3 @ W3.T + b3
            float p = b3[0];
#pragma unroll
            for (int q = 0; q < L3_; ++q) p += W3[q] * l3s[q];
            out[row] = p;
        }
        __syncthreads();   // protect sidx/accs reuse next row
    }
}

// ===========================================================================
// Fallback pair (round-0 structure, measured 1320 us) — used when cooperative
// launch is unavailable or fails.
// ===========================================================================
__global__ __launch_bounds__(256) void transpose_win(
    const float* __restrict__ W, _Float16* __restrict__ WTh)
{
    __shared__ float tile[64][65];
    const int jt = blockIdx.x * 64;
    const int ot = blockIdx.y * 64;
    {
        const int tx = threadIdx.x & 15;
        const int ty = threadIdx.x >> 4;
#pragma unroll
        for (int k = 0; k < 4; ++k) {
            const int o = ty + 16 * k;
            const v4f* p = (const v4f*)&W[(size_t)(ot + o) * IN_TOTAL + jt + 4 * tx];
            v4f v = __builtin_nontemporal_load(p);
            tile[4 * tx + 0][o] = v.x;
            tile[4 * tx + 1][o] = v.y;
            tile[4 * tx + 2][o] = v.z;
            tile[4 * tx + 3][o] = v.w;
        }
    }
    __syncthreads();
    {
        const int tx = threadIdx.x & 7;
        const int ty = threadIdx.x >> 3;
#pragma unroll
        for (int k = 0; k < 2; ++k) {
            const int j = ty + 32 * k;
            v8f v;
#pragma unroll
            for (int c = 0; c < 8; ++c) v[c] = tile[j][8 * tx + c];
            v8h h = __builtin_convertvector(v, v8h);
            *(v8h*)&WTh[(size_t)(jt + j) * L1 + ot + 8 * tx] = h;
        }
    }
}

__global__ __launch_bounds__(512) void nnue_fused(
    const float* __restrict__ wf, const float* __restrict__ bfeat,
    const _Float16* __restrict__ WTh,
    const float* __restrict__ b_in,
    const float* __restrict__ W1, const float* __restrict__ b1,
    const float* __restrict__ W2, const float* __restrict__ b2,
    const float* __restrict__ W3, const float* __restrict__ b3,
    float* __restrict__ out)
{
    const int b = blockIdx.x;
    const int t = threadIdx.x;

    __shared__ int   sidx[MAXIDX];
    __shared__ int   scnt;
    __shared__ float accs[8 * 64 * 9];
    __shared__ float l1s[L1];
    __shared__ float l2acc[L2];
    __shared__ float l2s[L2];
    __shared__ float l3s[L3_];

    if (t == 0) { scnt = 0; sidx[0] = 0; }
    __syncthreads();

    const v4u* wrow = (const v4u*)(wf    + (size_t)b * IN_PER_SIDE);
    const v4u* brow = (const v4u*)(bfeat + (size_t)b * IN_PER_SIDE);
    for (int i = t; i < IN_PER_SIDE / 4; i += 512) {
        v4u a = __builtin_nontemporal_load(wrow + i);
        v4u c = __builtin_nontemporal_load(brow + i);
        if (a.x | a.y | a.z | a.w) {
            if (a.x) sidx[atomicAdd(&scnt, 1)] = 4 * i + 0;
            if (a.y) sidx[atomicAdd(&scnt, 1)] = 4 * i + 1;
            if (a.z) sidx[atomicAdd(&scnt, 1)] = 4 * i + 2;
            if (a.w) sidx[atomicAdd(&scnt, 1)] = 4 * i + 3;
        }
        if (c.x | c.y | c.z | c.w) {
            if (c.x) sidx[atomicAdd(&scnt, 1)] = IN_PER_SIDE + 4 * i + 0;
            if (c.y) sidx[atomicAdd(&scnt, 1)] = IN_PER_SIDE + 4 * i + 1;
            if (c.z) sidx[atomicAdd(&scnt, 1)] = IN_PER_SIDE + 4 * i + 2;
            if (c.w) sidx[atomicAdd(&scnt, 1)] = IN_PER_SIDE + 4 * i + 3;
        }
    }
    __syncthreads();

    const int n = scnt;
    const int w = t >> 6;
    const int l = t & 63;
    const v8h* WTH8 = (const v8h*)WTh;

    v8f acc0 = {0, 0, 0, 0, 0, 0, 0, 0};
    v8f acc1 = {0, 0, 0, 0, 0, 0, 0, 0};
    const int J     = (n + 7) >> 3;
    const int Jeven = (J + 1) & ~1;
    {
        const int f0 = w, f1 = w + 8;
        v8h h0 = WTH8[(size_t)sidx[f0 < n ? f0 : 0] * 64 + l];
        float s0 = (f0 < n) ? 1.0f : 0.0f;
        v8h h1 = WTH8[(size_t)sidx[f1 < n ? f1 : 0] * 64 + l];
        float s1 = (f1 < n) ? 1.0f : 0.0f;
        for (int j = 2; j < Jeven; j += 2) {
            const int g0 = w + 8 * j, g1 = g0 + 8;
            v8h p0 = WTH8[(size_t)sidx[g0 < n ? g0 : 0] * 64 + l];
            const float u0 = (g0 < n) ? 1.0f : 0.0f;
            v8h p1 = WTH8[(size_t)sidx[g1 < n ? g1 : 0] * 64 + l];
            const float u1 = (g1 < n) ? 1.0f : 0.0f;
            acc0 += s0 * __builtin_convertvector(h0, v8f);
            acc1 += s1 * __builtin_convertvector(h1, v8f);
            h0 = p0; s0 = u0; h1 = p1; s1 = u1;
        }
        acc0 += s0 * __builtin_convertvector(h0, v8f);
        acc1 += s1 * __builtin_convertvector(h1, v8f);
    }
    acc0 += acc1;

    {
        float* dst = &accs[(w * 64 + l) * 9];
#pragma unroll
        for (int i = 0; i < 8; ++i) dst[i] = acc0[i];
    }
    __syncthreads();

    {
        const int ll = t >> 3, c = t & 7;
        float s = 0.0f;
#pragma unroll
        for (int ww = 0; ww < 8; ++ww) s += accs[(ww * 64 + ll) * 9 + c];
        l1s[t] = fminf(fmaxf(s + b_in[t], 0.0f), 1.0f);
    }
    __syncthreads();
    {
        const int kk = t >> 4;
        const int gg = t & 15;
        const float* wp = W1 + (size_t)kk * L1;
        float p = 0.0f;
        for (int o = gg; o < L1; o += 16) p += wp[o] * l1s[o];
#pragma unroll
        for (int off = 8; off > 0; off >>= 1) p += __shfl_down(p, off, 16);
        if (gg == 0) l2acc[kk] = p;
    }
    __syncthreads();
    if (t < L2) l2s[t] = fminf(fmaxf(l2acc[t] + b1[t], 0.0f), 1.0f);
    __syncthreads();
    if (t < L3_) {
        const float* wp = W2 + (size_t)t * L2;
        float p = b2[t];
#pragma unroll
        for (int q = 0; q < L2; ++q) p += wp[q] * l2s[q];
        l3s[t] = fminf(fmaxf(p, 0.0f), 1.0f);
    }
    __syncthreads();
    if (t == 0) {
        float p = b3[0];
#pragma unroll
        for (int q = 0; q < L3_; ++q) p += W3[q] * l3s[q];
        out[b] = p;
    }
}

__global__ __launch_bounds__(512) void nnue_fallback(
    const float* __restrict__ wf, const float* __restrict__ bfeat,
    const float* __restrict__ W_in, const float* __restrict__ b_in,
    const float* __restrict__ W1, const float* __restrict__ b1,
    const float* __restrict__ W2, const float* __restrict__ b2,
    const float* __restrict__ W3, const float* __restrict__ b3,
    float* __restrict__ out)
{
    const int b = blockIdx.x;
    const int t = threadIdx.x;
    __shared__ int   idxs[MAXIDX];
    __shared__ int   scnt;
    __shared__ float l1s[L1];
    __shared__ float l2acc[L2];
    __shared__ float l2s[L2];
    __shared__ float l3s[L3_];

    if (t == 0) scnt = 0;
    __syncthreads();
    const v4f* wrow = (const v4f*)(wf    + (size_t)b * IN_PER_SIDE);
    const v4f* brow = (const v4f*)(bfeat + (size_t)b * IN_PER_SIDE);
    for (int i = t; i < IN_PER_SIDE / 4; i += 512) {
        v4f v = wrow[i];
        if (v.x != 0.0f) idxs[atomicAdd(&scnt, 1)] = 4 * i + 0;
        if (v.y != 0.0f) idxs[atomicAdd(&scnt, 1)] = 4 * i + 1;
        if (v.z != 0.0f) idxs[atomicAdd(&scnt, 1)] = 4 * i + 2;
        if (v.w != 0.0f) idxs[atomicAdd(&scnt, 1)] = 4 * i + 3;
        v4f u = brow[i];
        if (u.x != 0.0f) idxs[atomicAdd(&scnt, 1)] = IN_PER_SIDE + 4 * i + 0;
        if (u.y != 0.0f) idxs[atomicAdd(&scnt, 1)] = IN_PER_SIDE + 4 * i + 1;
        if (u.z != 0.0f) idxs[atomicAdd(&scnt, 1)] = IN_PER_SIDE + 4 * i + 2;
        if (u.w != 0.0f) idxs[atomicAdd(&scnt, 1)] = IN_PER_SIDE + 4 * i + 3;
    }
    __syncthreads();
    const int n = scnt;
    float a0 = 0.0f;
    const float* row = W_in + (size_t)t * IN_TOTAL;
    for (int i = 0; i < n; ++i) a0 += row[idxs[i]];
    l1s[t] = fminf(fmaxf(b_in[t] + a0, 0.0f), 1.0f);
    __syncthreads();
    {
        const int k = t >> 4, g = t & 15;
        const float* wp = W1 + (size_t)k * L1;
        float p = 0.0f;
        for (int o = g; o < L1; o += 16) p += wp[o] * l1s[o];
#pragma unroll
        for (int off = 8; off > 0; off >>= 1) p += __shfl_down(p, off, 16);
        if (g == 0) l2acc[k] = p;
    }
    __syncthreads();
    if (t < L2) l2s[t] = fminf(fmaxf(l2acc[t] + b1[t], 0.0f), 1.0f);
    __syncthreads();
    if (t < L3_) {
        const float* wp = W2 + (size_t)t * L2;
        float p = b2[t];
#pragma unroll
        for (int q = 0; q < L2; ++q) p += wp[q] * l2s[q];
        l3s[t] = fminf(fmaxf(p, 0.0f), 1.0f);
    }
    __syncthreads();
    if (t == 0) {
        float p = b3[0];
#pragma unroll
        for (int q = 0; q < L3_; ++q) p += W3[q] * l3s[q];
        out[b] = p;
    }
}

extern "C" void kernel_launch(void* const* d_in, const int* in_sizes, int n_in,
                              void* d_out, int out_size, void* d_ws, size_t ws_size,
                              hipStream_t stream) {
    const float* wf   = (const float*)d_in[0];
    const float* bfeat= (const float*)d_in[1];
    const float* W_in = (const float*)d_in[2];
    const float* b_in = (const float*)d_in[3];
    const float* W1   = (const float*)d_in[4];
    const float* b1   = (const float*)d_in[5];
    const float* W2   = (const float*)d_in[6];
    const float* b2   = (const float*)d_in[7];
    const float* W3   = (const float*)d_in[8];
    const float* b3   = (const float*)d_in[9];
    float* out = (float*)d_out;

    // Cooperative grid size: computed once (host-side queries only; no stream
    // ops -> graph-capture safe). -1 = cooperative unavailable.
    static int g_grid = -2;
    if (g_grid == -2) {
        int dev = 0;
        hipDeviceProp_t prop{};
        int nb = 0;
        if (hipGetDevice(&dev) == hipSuccess &&
            hipGetDeviceProperties(&prop, dev) == hipSuccess &&
            prop.cooperativeLaunch &&
            hipOccupancyMaxActiveBlocksPerMultiprocessor(&nb, nnue_mega, 512, 0) == hipSuccess &&
            nb >= 1) {
            long cap = (long)nb * prop.multiProcessorCount;
            g_grid = (int)(cap < 1024 ? cap : 1024);
        } else {
            g_grid = -1;
        }
    }

    bool launched = false;
    if (ws_size >= WS_NEED && g_grid > 0) {
        char* ws = (char*)d_ws;
        _Float16* WTh = (_Float16*)ws;
        int* cnt  = (int*)(ws + CNT_OFF);
        int* idxg = (int*)(ws + IDX_OFF);

        const float* W_a = W_in;  _Float16* WTh_a = WTh;
        const float* wf_a = wf;   const float* bf_a = bfeat;
        int* cnt_a = cnt;         int* idxg_a = idxg;
        const float* bin_a = b_in;
        const float* W1_a = W1;   const float* b1_a = b1;
        const float* W2_a = W2;   const float* b2_a = b2;
        const float* W3_a = W3;   const float* b3_a = b3;
        float* out_a = out;
        void* args[] = {&W_a, &WTh_a, &wf_a, &bf_a, &cnt_a, &idxg_a,
                        &bin_a, &W1_a, &b1_a, &W2_a, &b2_a, &W3_a, &b3_a, &out_a};
        hipError_t e = hipLaunchCooperativeKernel(
            nnue_mega, dim3(g_grid), dim3(512), args, 0, stream);
        if (e == hipSuccess) {
            launched = true;
        } else {
            (void)hipGetLastError();   // clear; fall through to fallback
            g_grid = -1;               // don't retry cooperative path
        }
    }

    if (!launched) {
        if (ws_size >= WT_BYTES) {
            _Float16* WTh = (_Float16*)d_ws;
            dim3 grid(IN_TOTAL / 64, L1 / 64);   // (1280, 8)
            transpose_win<<<grid, 256, 0, stream>>>(W_in, WTh);
            nnue_fused<<<BATCH, 512, 0, stream>>>(
                wf, bfeat, WTh, b_in, W1, b1, W2, b2, W3, b3, out);
        } else {
            nnue_fallback<<<BATCH, 512, 0, stream>>>(
                wf, bfeat, W_in, b_in, W1, b1, W2, b2, W3, b3, out);
        }
    }
}

// Round 5
// 1385.284 us; speedup vs baseline: 1.1130x; 1.1130x over previous
//
#include <hip/hip_runtime.h>
#include <hip/hip_bf16.h>

// Problem constants (from reference)
#define IN_PER_SIDE   40960
#define IN_TOTAL      81920     // 2 * 40960
#define L1            512
#define L2            32
#define L3_           32
#define BATCH         4096
#define MAXIDX        128       // per-row index capacity (~60 used)

// clang-native vectors (HIP float4 is a class; builtins reject it)
typedef float        v4f __attribute__((ext_vector_type(4)));
typedef float        v8f __attribute__((ext_vector_type(8)));
typedef _Float16     v4h __attribute__((ext_vector_type(4)));
typedef _Float16     v8h __attribute__((ext_vector_type(8)));
typedef unsigned int v4u __attribute__((ext_vector_type(4)));

// WT stored as fp16: 81920 * 512 * 2 B = 83.9 MB (halves write + gather traffic;
// |W_in| <= 0.0035 so fp16 abs err ~1.7e-6/entry -> output err ~1e-5, thr 4.6e-4)
#define WT_BYTES ((size_t)IN_TOTAL * L1 * sizeof(_Float16))

// ---------------------------------------------------------------------------
// Kernel 1: LDS-tiled transpose W_in [512, 81920] f32 -> WTh [81920, 512] f16.
// 64x64 tiles, float4 PLAIN cached global reads (R4 evidence: nontemporal
// loads take an anomalous TCC path — mega's FETCH_SIZE was smaller than its
// nt-read bytes — and every nt-read stream we own runs well below copy BW;
// m13's 6.29 TB/s reference copy used plain loads). 16 B fp16 stores.
// LDS pad-65: 65 % 32 == 1 -> both access phases <=2-way aliased (free).
// ---------------------------------------------------------------------------
__global__ __launch_bounds__(256) void transpose_win(
    const float* __restrict__ W, _Float16* __restrict__ WTh)
{
    __shared__ float tile[64][65];
    const int jt = blockIdx.x * 64;           // input-feature tile base
    const int ot = blockIdx.y * 64;           // output-neuron tile base

    {
        const int tx = threadIdx.x & 15;      // float4 column
        const int ty = threadIdx.x >> 4;      // row
#pragma unroll
        for (int k = 0; k < 4; ++k) {
            const int o = ty + 16 * k;
            const v4f v = *(const v4f*)&W[(size_t)(ot + o) * IN_TOTAL + jt + 4 * tx];
            tile[4 * tx + 0][o] = v.x;
            tile[4 * tx + 1][o] = v.y;
            tile[4 * tx + 2][o] = v.z;
            tile[4 * tx + 3][o] = v.w;
        }
    }
    __syncthreads();
    {
        const int tx = threadIdx.x & 7;       // v8h column (8 fp16 = 16 B)
        const int ty = threadIdx.x >> 3;      // 0..31
#pragma unroll
        for (int k = 0; k < 2; ++k) {
            const int j = ty + 32 * k;
            v8f v;
#pragma unroll
            for (int c = 0; c < 8; ++c) v[c] = tile[j][8 * tx + c];
            v8h h = __builtin_convertvector(v, v8h);
            *(v8h*)&WTh[(size_t)(jt + j) * L1 + ot + 8 * tx] = h;
        }
    }
}

// ---------------------------------------------------------------------------
// Kernel 2: fused NNUE forward, one block per batch row, 512 threads.
//   Phase 1 (scan):   DE-INTERLEAVED single-stream loops — all 20 wf
//                     iterations, then all 20 bfeat iterations. Each wave's
//                     request stream is one contiguous 160 KB region at a
//                     time (previous versions alternated two streams 671 MB
//                     apart every iteration). Plain cached loads (see
//                     transpose comment re: nontemporal anomaly).
//   Phase 2 (gather): 8 waves x 64 lanes; one feature = 512 fp16 = 1 KB =
//                     ONE wave64 x 16 B coalesced load. Branchless masked
//                     2-deep pipeline: uniform trip count, OOB slots read
//                     sidx[0] with scale 0.
//   Phase 3-5: tiny dense layers, shuffle reductions, no atomics.
// Scan (HBM-bound) and gather/MLP (latency-bound) overlap across blocks.
// ---------------------------------------------------------------------------
__global__ __launch_bounds__(512) void nnue_fused(
    const float* __restrict__ wf, const float* __restrict__ bfeat,
    const _Float16* __restrict__ WTh,
    const float* __restrict__ b_in,
    const float* __restrict__ W1, const float* __restrict__ b1,
    const float* __restrict__ W2, const float* __restrict__ b2,
    const float* __restrict__ W3, const float* __restrict__ b3,
    float* __restrict__ out)
{
    const int b = blockIdx.x;
    const int t = threadIdx.x;

    __shared__ int   sidx[MAXIDX];
    __shared__ int   scnt;
    __shared__ float accs[8 * 64 * 9];   // [wave][lane][8 neurons + pad]
    __shared__ float l1s[L1];
    __shared__ float l2acc[L2];
    __shared__ float l2s[L2];
    __shared__ float l3s[L3_];

    if (t == 0) { scnt = 0; sidx[0] = 0; }   // sidx[0] init: safe OOB target
    __syncthreads();

    // ---- Phase 1: scan, one stream at a time ({0.0,1.0} bit patterns)
    const v4u* wrow = (const v4u*)(wf    + (size_t)b * IN_PER_SIDE);
    const v4u* brow = (const v4u*)(bfeat + (size_t)b * IN_PER_SIDE);
    const int nvec = IN_PER_SIDE / 4;  // 10240 -> exactly 20 iters @ stride 512

    for (int i = t; i < nvec; i += 512) {
        const v4u a = wrow[i];
        if (a.x | a.y | a.z | a.w) {
            if (a.x) sidx[atomicAdd(&scnt, 1)] = 4 * i + 0;
            if (a.y) sidx[atomicAdd(&scnt, 1)] = 4 * i + 1;
            if (a.z) sidx[atomicAdd(&scnt, 1)] = 4 * i + 2;
            if (a.w) sidx[atomicAdd(&scnt, 1)] = 4 * i + 3;
        }
    }
    for (int i = t; i < nvec; i += 512) {
        const v4u c = brow[i];
        if (c.x | c.y | c.z | c.w) {
            if (c.x) sidx[atomicAdd(&scnt, 1)] = IN_PER_SIDE + 4 * i + 0;
            if (c.y) sidx[atomicAdd(&scnt, 1)] = IN_PER_SIDE + 4 * i + 1;
            if (c.z) sidx[atomicAdd(&scnt, 1)] = IN_PER_SIDE + 4 * i + 2;
            if (c.w) sidx[atomicAdd(&scnt, 1)] = IN_PER_SIDE + 4 * i + 3;
        }
    }
    __syncthreads();

    // ---- Phase 2: gather active WTh columns; wave w, lane l.
    const int n = scnt;
    const int w = t >> 6;          // wave 0..7
    const int l = t & 63;          // lane 0..63
    const v8h* WTH8 = (const v8h*)WTh;   // feature f -> WTH8[f*64 + l]

    v8f acc0 = {0, 0, 0, 0, 0, 0, 0, 0};
    v8f acc1 = {0, 0, 0, 0, 0, 0, 0, 0};
    const int J     = (n + 7) >> 3;        // masked per-wave trip count
    const int Jeven = (J + 1) & ~1;        // round up to pair granularity

    {
        const int f0 = w, f1 = w + 8;
        v8h h0 = WTH8[(size_t)sidx[f0 < n ? f0 : 0] * 64 + l];
        float s0 = (f0 < n) ? 1.0f : 0.0f;
        v8h h1 = WTH8[(size_t)sidx[f1 < n ? f1 : 0] * 64 + l];
        float s1 = (f1 < n) ? 1.0f : 0.0f;
        for (int j = 2; j < Jeven; j += 2) {
            const int g0 = w + 8 * j, g1 = g0 + 8;
            v8h p0 = WTH8[(size_t)sidx[g0 < n ? g0 : 0] * 64 + l];
            const float u0 = (g0 < n) ? 1.0f : 0.0f;
            v8h p1 = WTH8[(size_t)sidx[g1 < n ? g1 : 0] * 64 + l];
            const float u1 = (g1 < n) ? 1.0f : 0.0f;
            acc0 += s0 * __builtin_convertvector(h0, v8f);
            acc1 += s1 * __builtin_convertvector(h1, v8f);
            h0 = p0; s0 = u0; h1 = p1; s1 = u1;
        }
        acc0 += s0 * __builtin_convertvector(h0, v8f);
        acc1 += s1 * __builtin_convertvector(h1, v8f);
    }
    acc0 += acc1;

    // scalar LDS stores at pad-9 stride: bank = (9*l + i) % 32, 9 odd ->
    // distinct over 32 lanes per i -> conflict-free.
    {
        float* dst = &accs[(w * 64 + l) * 9];
#pragma unroll
        for (int i = 0; i < 8; ++i) dst[i] = acc0[i];
    }
    __syncthreads();

    // ---- reduce waves + bias + clipped ReLU; thread t = neuron t.
    {
        const int ll = t >> 3, c = t & 7;
        float s = 0.0f;
#pragma unroll
        for (int ww = 0; ww < 8; ++ww) s += accs[(ww * 64 + ll) * 9 + c];
        l1s[t] = fminf(fmaxf(s + b_in[t], 0.0f), 1.0f);
    }
    __syncthreads();

    // ---- Phase 3: l2 = clip(l1 @ W1.T + b1): output k owned by 16 lanes
    {
        const int kk = t >> 4;
        const int gg = t & 15;
        const float* wp = W1 + (size_t)kk * L1;
        float p = 0.0f;
        for (int o = gg; o < L1; o += 16) p += wp[o] * l1s[o];
#pragma unroll
        for (int off = 8; off > 0; off >>= 1) p += __shfl_down(p, off, 16);
        if (gg == 0) l2acc[kk] = p;
    }
    __syncthreads();
    if (t < L2) l2s[t] = fminf(fmaxf(l2acc[t] + b1[t], 0.0f), 1.0f);
    __syncthreads();

    // ---- Phase 4: l3 = clip(l2 @ W2.T + b2), 32x32
    if (t < L3_) {
        const float* wp = W2 + (size_t)t * L2;
        float p = b2[t];
#pragma unroll
        for (int q = 0; q < L2; ++q) p += wp[q] * l2s[q];
        l3s[t] = fminf(fmaxf(p, 0.0f), 1.0f);
    }
    __syncthreads();

    // ---- Phase 5: out = l3 @ W3.T + b3
    if (t == 0) {
        float p = b3[0];
#pragma unroll
        for (int q = 0; q < L3_; ++q) p += W3[q] * l3s[q];
        out[b] = p;
    }
}

// ---------------------------------------------------------------------------
// Fallback (ws too small for WTh): fused kernel reading W_in columns
// directly. Correct but slow; not expected to run (ws ~2.5 GiB >> 84 MB).
// ---------------------------------------------------------------------------
__global__ __launch_bounds__(512) void nnue_fallback(
    const float* __restrict__ wf, const float* __restrict__ bfeat,
    const float* __restrict__ W_in, const float* __restrict__ b_in,
    const float* __restrict__ W1, const float* __restrict__ b1,
    const float* __restrict__ W2, const float* __restrict__ b2,
    const float* __restrict__ W3, const float* __restrict__ b3,
    float* __restrict__ out)
{
    const int b = blockIdx.x;
    const int t = threadIdx.x;
    __shared__ int   idxs[MAXIDX];
    __shared__ int   scnt;
    __shared__ float l1s[L1];
    __shared__ float l2acc[L2];
    __shared__ float l2s[L2];
    __shared__ float l3s[L3_];

    if (t == 0) scnt = 0;
    __syncthreads();
    const v4f* wrow = (const v4f*)(wf    + (size_t)b * IN_PER_SIDE);
    const v4f* brow = (const v4f*)(bfeat + (size_t)b * IN_PER_SIDE);
    for (int i = t; i < IN_PER_SIDE / 4; i += 512) {
        v4f v = wrow[i];
        if (v.x != 0.0f) idxs[atomicAdd(&scnt, 1)] = 4 * i + 0;
        if (v.y != 0.0f) idxs[atomicAdd(&scnt, 1)] = 4 * i + 1;
        if (v.z != 0.0f) idxs[atomicAdd(&scnt, 1)] = 4 * i + 2;
        if (v.w != 0.0f) idxs[atomicAdd(&scnt, 1)] = 4 * i + 3;
        v4f u = brow[i];
        if (u.x != 0.0f) idxs[atomicAdd(&scnt, 1)] = IN_PER_SIDE + 4 * i + 0;
        if (u.y != 0.0f) idxs[atomicAdd(&scnt, 1)] = IN_PER_SIDE + 4 * i + 1;
        if (u.z != 0.0f) idxs[atomicAdd(&scnt, 1)] = IN_PER_SIDE + 4 * i + 2;
        if (u.w != 0.0f) idxs[atomicAdd(&scnt, 1)] = IN_PER_SIDE + 4 * i + 3;
    }
    __syncthreads();
    const int n = scnt;
    float a0 = 0.0f;
    const float* row = W_in + (size_t)t * IN_TOTAL;
    for (int i = 0; i < n; ++i) a0 += row[idxs[i]];
    l1s[t] = fminf(fmaxf(b_in[t] + a0, 0.0f), 1.0f);
    __syncthreads();
    {
        const int k = t >> 4, g = t & 15;
        const float* wp = W1 + (size_t)k * L1;
        float p = 0.0f;
        for (int o = g; o < L1; o += 16) p += wp[o] * l1s[o];
#pragma unroll
        for (int off = 8; off > 0; off >>= 1) p += __shfl_down(p, off, 16);
        if (g == 0) l2acc[k] = p;
    }
    __syncthreads();
    if (t < L2) l2s[t] = fminf(fmaxf(l2acc[t] + b1[t], 0.0f), 1.0f);
    __syncthreads();
    if (t < L3_) {
        const float* wp = W2 + (size_t)t * L2;
        float p = b2[t];
#pragma unroll
        for (int q = 0; q < L2; ++q) p += wp[q] * l2s[q];
        l3s[t] = fminf(fmaxf(p, 0.0f), 1.0f);
    }
    __syncthreads();
    if (t == 0) {
        float p = b3[0];
#pragma unroll
        for (int q = 0; q < L3_; ++q) p += W3[q] * l3s[q];
        out[b] = p;
    }
}

extern "C" void kernel_launch(void* const* d_in, const int* in_sizes, int n_in,
                              void* d_out, int out_size, void* d_ws, size_t ws_size,
                              hipStream_t stream) {
    const float* wf   = (const float*)d_in[0];
    const float* bfeat= (const float*)d_in[1];
    const float* W_in = (const float*)d_in[2];
    const float* b_in = (const float*)d_in[3];
    const float* W1   = (const float*)d_in[4];
    const float* b1   = (const float*)d_in[5];
    const float* W2   = (const float*)d_in[6];
    const float* b2   = (const float*)d_in[7];
    const float* W3   = (const float*)d_in[8];
    const float* b3   = (const float*)d_in[9];
    float* out = (float*)d_out;

    if (ws_size >= WT_BYTES) {
        _Float16* WTh = (_Float16*)d_ws;
        dim3 grid(IN_TOTAL / 64, L1 / 64);   // (1280, 8)
        transpose_win<<<grid, 256, 0, stream>>>(W_in, WTh);
        nnue_fused<<<BATCH, 512, 0, stream>>>(
            wf, bfeat, WTh, b_in, W1, b1, W2, b2, W3, b3, out);
    } else {
        nnue_fallback<<<BATCH, 512, 0, stream>>>(
            wf, bfeat, W_in, b_in, W1, b1, W2, b2, W3, b3, out);
    }
}

// Round 6
// 1372.766 us; speedup vs baseline: 1.1231x; 1.0091x over previous
//
#include <hip/hip_runtime.h>
#include <hip/hip_bf16.h>

// Problem constants (from reference)
#define IN_PER_SIDE   40960
#define IN_TOTAL      81920     // 2 * 40960
#define L1            512
#define L2            32
#define L3_           32
#define BATCH         4096
#define MAXIDX        128       // per-row index capacity (~60 used)

// clang-native vectors (HIP float4 is a class; builtins reject it)
typedef float        v4f __attribute__((ext_vector_type(4)));
typedef float        v8f __attribute__((ext_vector_type(8)));
typedef _Float16     v4h __attribute__((ext_vector_type(4)));
typedef _Float16     v8h __attribute__((ext_vector_type(8)));
typedef unsigned int v4u __attribute__((ext_vector_type(4)));

// ws layout:
//   [0, WT_BYTES)      : WTh fp16 transposed W_in [81920][512]  (83.9 MB)
//   [CNT_OFF, +16 KB)  : cnt, per-row active count
//   [IDX_OFF, +2 MB)   : idxg, per-row compact feature lists
#define WT_BYTES ((size_t)IN_TOTAL * L1 * sizeof(_Float16))
#define CNT_OFF  WT_BYTES
#define IDX_OFF  (WT_BYTES + 16384)
#define WS_NEED  (IDX_OFF + (size_t)BATCH * MAXIDX * 4)

// ---------------------------------------------------------------------------
// Kernel 0: zero per-row counters (ws is poisoned between iterations).
// ---------------------------------------------------------------------------
__global__ __launch_bounds__(256) void zero_cnt(int* __restrict__ cnt)
{
    cnt[blockIdx.x * 256 + threadIdx.x] = 0;
}

// ---------------------------------------------------------------------------
// Kernel 1: LDS-tiled transpose W_in [512, 81920] f32 -> WTh [81920, 512] f16.
// R0 structure (best measured). 64x64 tiles, nt float4 reads (W_in used
// once), 16 B fp16 stores. Pad-65 -> <=2-way bank alias (free).
// ---------------------------------------------------------------------------
__global__ __launch_bounds__(256) void transpose_win(
    const float* __restrict__ W, _Float16* __restrict__ WTh)
{
    __shared__ float tile[64][65];
    const int jt = blockIdx.x * 64;           // input-feature tile base
    const int ot = blockIdx.y * 64;           // output-neuron tile base

    {
        const int tx = threadIdx.x & 15;      // float4 column
        const int ty = threadIdx.x >> 4;      // row
#pragma unroll
        for (int k = 0; k < 4; ++k) {
            const int o = ty + 16 * k;
            const v4f* p = (const v4f*)&W[(size_t)(ot + o) * IN_TOTAL + jt + 4 * tx];
            v4f v = __builtin_nontemporal_load(p);
            tile[4 * tx + 0][o] = v.x;
            tile[4 * tx + 1][o] = v.y;
            tile[4 * tx + 2][o] = v.z;
            tile[4 * tx + 3][o] = v.w;
        }
    }
    __syncthreads();
    {
        const int tx = threadIdx.x & 7;       // v8h column (8 fp16 = 16 B)
        const int ty = threadIdx.x >> 3;      // 0..31
#pragma unroll
        for (int k = 0; k < 2; ++k) {
            const int j = ty + 32 * k;
            v8f v;
#pragma unroll
            for (int c = 0; c < 8; ++c) v[c] = tile[j][8 * tx + c];
            v8h h = __builtin_convertvector(v, v8h);
            *(v8h*)&WTh[(size_t)(jt + j) * L1 + ot + 8 * tx] = h;
        }
    }
}

// ---------------------------------------------------------------------------
// Kernel 2: DEDICATED scan. One block per (row, side): 8192 blocks x 256
// threads, each streams one contiguous 160 KB region and nothing else —
// shaped like the 6.4 TB/s fill kernel (256-thread blocks, no tail phases).
// Mechanism under test: in all prior variants the scan shared its kernel
// with latency/barrier-bound phases (gather, MLP, transpose, grid.sync) and
// never exceeded ~3.4 TB/s; a pure stream+compact kernel should run at the
// fill's BW. Nonzeros -> LDS compact -> ONE global atomicAdd per block for
// the row base (2/row, contention-free) -> coalesced index burst.
// ---------------------------------------------------------------------------
__global__ __launch_bounds__(256) void scan_rows(
    const float* __restrict__ wf, const float* __restrict__ bfeat,
    int* __restrict__ cnt, int* __restrict__ idxg)
{
    const int r = blockIdx.x >> 1;          // batch row
    const int s = blockIdx.x & 1;           // side: 0=wf, 1=bfeat
    const int t = threadIdx.x;

    __shared__ int lidx[MAXIDX];
    __shared__ int lcnt;
    __shared__ int lbase;
    if (t == 0) lcnt = 0;
    __syncthreads();

    const float* src = s ? bfeat : wf;
    const int    off = s ? IN_PER_SIDE : 0;
    const v4u* row = (const v4u*)(src + (size_t)r * IN_PER_SIDE);

    // 10240 v4u / 256 threads = exactly 40 per thread; ~0.3% hit the push.
    for (int i = t; i < IN_PER_SIDE / 4; i += 256) {
        const v4u a = __builtin_nontemporal_load(row + i);
        if (a.x | a.y | a.z | a.w) {
            if (a.x) { int p = atomicAdd(&lcnt, 1); if (p < MAXIDX) lidx[p] = off + 4 * i + 0; }
            if (a.y) { int p = atomicAdd(&lcnt, 1); if (p < MAXIDX) lidx[p] = off + 4 * i + 1; }
            if (a.z) { int p = atomicAdd(&lcnt, 1); if (p < MAXIDX) lidx[p] = off + 4 * i + 2; }
            if (a.w) { int p = atomicAdd(&lcnt, 1); if (p < MAXIDX) lidx[p] = off + 4 * i + 3; }
        }
    }
    __syncthreads();
    const int nb = min(lcnt, MAXIDX);
    if (t == 0) lbase = atomicAdd(&cnt[r], nb);   // device-scope, 2 per row
    __syncthreads();
    const int b0 = lbase;
    if (t < nb && b0 + t < MAXIDX)
        idxg[(size_t)r * MAXIDX + b0 + t] = lidx[t];
}

// ---------------------------------------------------------------------------
// Kernel 3: gather + MLP. One block per batch row, 512 threads.
//   Gather: 8 waves x 64 lanes; one feature = 512 fp16 = 1 KB = ONE wave64 x
//   16 B coalesced load from cache-warm WTh. Branchless masked 2-deep
//   pipeline (OOB slots read sidx[0] with scale 0). Then tiny dense layers
//   via shuffle reductions.
// ---------------------------------------------------------------------------
__global__ __launch_bounds__(512) void nnue_gather(
    const _Float16* __restrict__ WTh,
    const int* __restrict__ cnt, const int* __restrict__ idxg,
    const float* __restrict__ b_in,
    const float* __restrict__ W1, const float* __restrict__ b1,
    const float* __restrict__ W2, const float* __restrict__ b2,
    const float* __restrict__ W3, const float* __restrict__ b3,
    float* __restrict__ out)
{
    const int b = blockIdx.x;
    const int t = threadIdx.x;

    __shared__ int   sidx[MAXIDX];
    __shared__ float accs[8 * 64 * 9];   // [wave][lane][8 neurons + pad]
    __shared__ float l1s[L1];
    __shared__ float l2acc[L2];
    __shared__ float l2s[L2];
    __shared__ float l3s[L3_];

    const int n = min(cnt[b], MAXIDX);
    if (t < MAXIDX) {
        const int g = idxg[(size_t)b * MAXIDX + t];
        sidx[t] = (t < n) ? g : 0;       // OOB slots -> valid feature 0
    }
    __syncthreads();

    // ---- gather active WTh columns; wave w, lane l.
    const int w = t >> 6;          // wave 0..7
    const int l = t & 63;          // lane 0..63
    const v8h* WTH8 = (const v8h*)WTh;   // feature f -> WTH8[f*64 + l]

    v8f acc0 = {0, 0, 0, 0, 0, 0, 0, 0};
    v8f acc1 = {0, 0, 0, 0, 0, 0, 0, 0};
    const int J     = (n + 7) >> 3;        // masked per-wave trip count
    const int Jeven = (J + 1) & ~1;        // round up to pair granularity

    {
        const int f0 = w, f1 = w + 8;
        v8h h0 = WTH8[(size_t)sidx[f0 < n ? f0 : 0] * 64 + l];
        float s0 = (f0 < n) ? 1.0f : 0.0f;
        v8h h1 = WTH8[(size_t)sidx[f1 < n ? f1 : 0] * 64 + l];
        float s1 = (f1 < n) ? 1.0f : 0.0f;
        for (int j = 2; j < Jeven; j += 2) {
            const int g0 = w + 8 * j, g1 = g0 + 8;
            v8h p0 = WTH8[(size_t)sidx[g0 < n ? g0 : 0] * 64 + l];
            const float u0 = (g0 < n) ? 1.0f : 0.0f;
            v8h p1 = WTH8[(size_t)sidx[g1 < n ? g1 : 0] * 64 + l];
            const float u1 = (g1 < n) ? 1.0f : 0.0f;
            acc0 += s0 * __builtin_convertvector(h0, v8f);
            acc1 += s1 * __builtin_convertvector(h1, v8f);
            h0 = p0; s0 = u0; h1 = p1; s1 = u1;
        }
        acc0 += s0 * __builtin_convertvector(h0, v8f);
        acc1 += s1 * __builtin_convertvector(h1, v8f);
    }
    acc0 += acc1;

    // scalar LDS stores at pad-9 stride: bank = (9*l + i) % 32, 9 odd ->
    // distinct over 32 lanes per i -> conflict-free.
    {
        float* dst = &accs[(w * 64 + l) * 9];
#pragma unroll
        for (int i = 0; i < 8; ++i) dst[i] = acc0[i];
    }
    __syncthreads();

    // ---- reduce waves + bias + clipped ReLU; thread t = neuron t.
    {
        const int ll = t >> 3, c = t & 7;
        float s = 0.0f;
#pragma unroll
        for (int ww = 0; ww < 8; ++ww) s += accs[(ww * 64 + ll) * 9 + c];
        l1s[t] = fminf(fmaxf(s + b_in[t], 0.0f), 1.0f);
    }
    __syncthreads();

    // ---- l2 = clip(l1 @ W1.T + b1): output k owned by 16 lanes
    {
        const int kk = t >> 4;
        const int gg = t & 15;
        const float* wp = W1 + (size_t)kk * L1;
        float p = 0.0f;
        for (int o = gg; o < L1; o += 16) p += wp[o] * l1s[o];
#pragma unroll
        for (int off = 8; off > 0; off >>= 1) p += __shfl_down(p, off, 16);
        if (gg == 0) l2acc[kk] = p;
    }
    __syncthreads();
    if (t < L2) l2s[t] = fminf(fmaxf(l2acc[t] + b1[t], 0.0f), 1.0f);
    __syncthreads();

    // ---- l3 = clip(l2 @ W2.T + b2), 32x32
    if (t < L3_) {
        const float* wp = W2 + (size_t)t * L2;
        float p = b2[t];
#pragma unroll
        for (int q = 0; q < L2; ++q) p += wp[q] * l2s[q];
        l3s[t] = fminf(fmaxf(p, 0.0f), 1.0f);
    }
    __syncthreads();

    // ---- out = l3 @ W3.T + b3
    if (t == 0) {
        float p = b3[0];
#pragma unroll
        for (int q = 0; q < L3_; ++q) p += W3[q] * l3s[q];
        out[b] = p;
    }
}

// ---------------------------------------------------------------------------
// Fallback (ws too small): fused kernel reading W_in columns directly.
// Correct but slow; not expected to run (ws ~2.5 GiB >> 87 MB).
// ---------------------------------------------------------------------------
__global__ __launch_bounds__(512) void nnue_fallback(
    const float* __restrict__ wf, const float* __restrict__ bfeat,
    const float* __restrict__ W_in, const float* __restrict__ b_in,
    const float* __restrict__ W1, const float* __restrict__ b1,
    const float* __restrict__ W2, const float* __restrict__ b2,
    const float* __restrict__ W3, const float* __restrict__ b3,
    float* __restrict__ out)
{
    const int b = blockIdx.x;
    const int t = threadIdx.x;
    __shared__ int   idxs[MAXIDX];
    __shared__ int   scnt;
    __shared__ float l1s[L1];
    __shared__ float l2acc[L2];
    __shared__ float l2s[L2];
    __shared__ float l3s[L3_];

    if (t == 0) scnt = 0;
    __syncthreads();
    const v4f* wrow = (const v4f*)(wf    + (size_t)b * IN_PER_SIDE);
    const v4f* brow = (const v4f*)(bfeat + (size_t)b * IN_PER_SIDE);
    for (int i = t; i < IN_PER_SIDE / 4; i += 512) {
        v4f v = wrow[i];
        if (v.x != 0.0f) idxs[atomicAdd(&scnt, 1)] = 4 * i + 0;
        if (v.y != 0.0f) idxs[atomicAdd(&scnt, 1)] = 4 * i + 1;
        if (v.z != 0.0f) idxs[atomicAdd(&scnt, 1)] = 4 * i + 2;
        if (v.w != 0.0f) idxs[atomicAdd(&scnt, 1)] = 4 * i + 3;
        v4f u = brow[i];
        if (u.x != 0.0f) idxs[atomicAdd(&scnt, 1)] = IN_PER_SIDE + 4 * i + 0;
        if (u.y != 0.0f) idxs[atomicAdd(&scnt, 1)] = IN_PER_SIDE + 4 * i + 1;
        if (u.z != 0.0f) idxs[atomicAdd(&scnt, 1)] = IN_PER_SIDE + 4 * i + 2;
        if (u.w != 0.0f) idxs[atomicAdd(&scnt, 1)] = IN_PER_SIDE + 4 * i + 3;
    }
    __syncthreads();
    const int n = scnt;
    float a0 = 0.0f;
    const float* row = W_in + (size_t)t * IN_TOTAL;
    for (int i = 0; i < n; ++i) a0 += row[idxs[i]];
    l1s[t] = fminf(fmaxf(b_in[t] + a0, 0.0f), 1.0f);
    __syncthreads();
    {
        const int k = t >> 4, g = t & 15;
        const float* wp = W1 + (size_t)k * L1;
        float p = 0.0f;
        for (int o = g; o < L1; o += 16) p += wp[o] * l1s[o];
#pragma unroll
        for (int off = 8; off > 0; off >>= 1) p += __shfl_down(p, off, 16);
        if (g == 0) l2acc[k] = p;
    }
    __syncthreads();
    if (t < L2) l2s[t] = fminf(fmaxf(l2acc[t] + b1[t], 0.0f), 1.0f);
    __syncthreads();
    if (t < L3_) {
        const float* wp = W2 + (size_t)t * L2;
        float p = b2[t];
#pragma unroll
        for (int q = 0; q < L2; ++q) p += wp[q] * l2s[q];
        l3s[t] = fminf(fmaxf(p, 0.0f), 1.0f);
    }
    __syncthreads();
    if (t == 0) {
        float p = b3[0];
#pragma unroll
        for (int q = 0; q < L3_; ++q) p += W3[q] * l3s[q];
        out[b] = p;
    }
}

extern "C" void kernel_launch(void* const* d_in, const int* in_sizes, int n_in,
                              void* d_out, int out_size, void* d_ws, size_t ws_size,
                              hipStream_t stream) {
    const float* wf   = (const float*)d_in[0];
    const float* bfeat= (const float*)d_in[1];
    const float* W_in = (const float*)d_in[2];
    const float* b_in = (const float*)d_in[3];
    const float* W1   = (const float*)d_in[4];
    const float* b1   = (const float*)d_in[5];
    const float* W2   = (const float*)d_in[6];
    const float* b2   = (const float*)d_in[7];
    const float* W3   = (const float*)d_in[8];
    const float* b3   = (const float*)d_in[9];
    float* out = (float*)d_out;

    if (ws_size >= WS_NEED) {
        char* ws = (char*)d_ws;
        _Float16* WTh = (_Float16*)ws;
        int* cnt  = (int*)(ws + CNT_OFF);
        int* idxg = (int*)(ws + IDX_OFF);

        zero_cnt<<<BATCH / 256, 256, 0, stream>>>(cnt);
        {
            dim3 grid(IN_TOTAL / 64, L1 / 64);   // (1280, 8)
            transpose_win<<<grid, 256, 0, stream>>>(W_in, WTh);
        }
        scan_rows<<<2 * BATCH, 256, 0, stream>>>(wf, bfeat, cnt, idxg);
        nnue_gather<<<BATCH, 512, 0, stream>>>(
            WTh, cnt, idxg, b_in, W1, b1, W2, b2, W3, b3, out);
    } else {
        nnue_fallback<<<BATCH, 512, 0, stream>>>(
            wf, bfeat, W_in, b_in, W1, b1, W2, b2, W3, b3, out);
    }
}

// Round 7
// 1318.418 us; speedup vs baseline: 1.1694x; 1.0412x over previous
//
#include <hip/hip_runtime.h>
#include <hip/hip_bf16.h>

// Problem constants (from reference)
#define IN_PER_SIDE   40960
#define IN_TOTAL      81920     // 2 * 40960
#define L1            512
#define L2            32
#define L3_           32
#define BATCH         4096
#define MAXIDX        128       // per-row index capacity (~60 used)

// clang-native vectors (HIP float4 is a class; builtins reject it)
typedef float    v4f __attribute__((ext_vector_type(4)));
typedef float    v8f __attribute__((ext_vector_type(8)));
typedef _Float16 v4h __attribute__((ext_vector_type(4)));
typedef _Float16 v8h __attribute__((ext_vector_type(8)));

// WT stored as fp16: 81920 * 512 * 2 B = 83.9 MB (halves write + gather traffic;
// |W_in| <= 0.0035 so fp16 abs err ~1.7e-6/entry -> output err ~1e-5, thr 4.6e-4)
#define WT_BYTES ((size_t)IN_TOTAL * L1 * sizeof(_Float16))

// ---------------------------------------------------------------------------
// SESSION VERDICT (rounds 0-6): this file is the measured optimum (1320 us).
// Structures tried and rejected: scan ILP pipeline (R1 null), prep-fused
// transpose+scan w/ global atomics (R2 -80us), branch-free load clauses
// (R3 null), cooperative mega-kernel (R4 -220us; direct counters: 18% HBM,
// 6.6% VALU, 73% occ = latency-path-bound, not BW-saturated), plain loads +
// de-interleaved streams (R5 -65us), dedicated fill-shaped scan kernel
// (R6 -52us). Read streams cap at ~3.4 TB/s on this input regardless of
// kernel shape; the 6.4 TB/s fill figure is write-side. Remaining billed
// time (~840us) is two 2.68 GB harness ws-poison fills (fixed cost).
// ---------------------------------------------------------------------------

// ---------------------------------------------------------------------------
// Kernel 1: LDS-tiled transpose W_in [512, 81920] f32 -> WTh [81920, 512] f16.
// 64x64 tiles, float4 global reads (nontemporal: W_in used once, keep L3 for
// WTh), 8 B fp16 writes (16 lanes x 8 B = 128 B contiguous per row segment).
// ---------------------------------------------------------------------------
__global__ __launch_bounds__(256) void transpose_win(
    const float* __restrict__ W, _Float16* __restrict__ WTh)
{
    __shared__ float tile[64][65];
    const int jt = blockIdx.x * 64;           // input-feature tile base
    const int ot = blockIdx.y * 64;           // output-neuron tile base
    const int tx = threadIdx.x & 15;          // float4 column
    const int ty = threadIdx.x >> 4;          // row

#pragma unroll
    for (int k = 0; k < 4; ++k) {
        const int o = ty + 16 * k;
        const v4f* p = (const v4f*)&W[(size_t)(ot + o) * IN_TOTAL + jt + 4 * tx];
        v4f v = __builtin_nontemporal_load(p);
        tile[4 * tx + 0][o] = v.x;
        tile[4 * tx + 1][o] = v.y;
        tile[4 * tx + 2][o] = v.z;
        tile[4 * tx + 3][o] = v.w;
    }
    __syncthreads();
#pragma unroll
    for (int k = 0; k < 4; ++k) {
        const int j = ty + 16 * k;
        v4f v;
        v.x = tile[j][4 * tx + 0];
        v.y = tile[j][4 * tx + 1];
        v.z = tile[j][4 * tx + 2];
        v.w = tile[j][4 * tx + 3];
        v4h h = __builtin_convertvector(v, v4h);
        *(v4h*)&WTh[(size_t)(jt + j) * L1 + ot + 4 * tx] = h;
    }
}

// ---------------------------------------------------------------------------
// Kernel 2: fused NNUE forward, one block per batch row, 512 threads.
//   Phase 1 (scan):   nontemporal float4 stream; {0,1} values -> sum test
//                     rejects all-zero vectors with one compare.
//   Phase 2 (gather): 8 waves x 64 lanes; one feature = 512 fp16 = 1 KB =
//                     ONE wave64 x 16 B coalesced load. Wave w owns features
//                     w, w+8, ... (8 features in flight; unroll 2 -> 16).
//                     fp32 accumulate; cross-wave reduce via pad-9 LDS
//                     (9 odd -> every access <=2-way bank alias = free).
//   Phase 3-5: tiny dense layers, shuffle reductions, no atomics.
// Scan (HBM-BW-bound) and gather (L3-latency-bound) overlap across blocks.
// ---------------------------------------------------------------------------
__global__ __launch_bounds__(512) void nnue_fused(
    const float* __restrict__ wf, const float* __restrict__ bfeat,
    const _Float16* __restrict__ WTh,
    const float* __restrict__ b_in,
    const float* __restrict__ W1, const float* __restrict__ b1,
    const float* __restrict__ W2, const float* __restrict__ b2,
    const float* __restrict__ W3, const float* __restrict__ b3,
    float* __restrict__ out)
{
    const int b = blockIdx.x;
    const int t = threadIdx.x;

    __shared__ int   sidx[MAXIDX];
    __shared__ int   scnt;
    __shared__ float accs[8 * 64 * 9];   // [wave][lane][8 neurons + pad]
    __shared__ float l1s[L1];
    __shared__ float l2acc[L2];
    __shared__ float l2s[L2];
    __shared__ float l3s[L3_];

    if (t == 0) scnt = 0;
    __syncthreads();

    // ---- Phase 1: scan both perspective rows (values are exactly 0.0/1.0)
    const v4f* wrow = (const v4f*)(wf    + (size_t)b * IN_PER_SIDE);
    const v4f* brow = (const v4f*)(bfeat + (size_t)b * IN_PER_SIDE);
    const int nvec = IN_PER_SIDE / 4;  // 10240 float4 per side

    for (int i = t; i < nvec; i += 512) {
        v4f v = __builtin_nontemporal_load(wrow + i);
        if (v.x + v.y + v.z + v.w != 0.0f) {
            if (v.x != 0.0f) sidx[atomicAdd(&scnt, 1)] = 4 * i + 0;
            if (v.y != 0.0f) sidx[atomicAdd(&scnt, 1)] = 4 * i + 1;
            if (v.z != 0.0f) sidx[atomicAdd(&scnt, 1)] = 4 * i + 2;
            if (v.w != 0.0f) sidx[atomicAdd(&scnt, 1)] = 4 * i + 3;
        }
        v4f u = __builtin_nontemporal_load(brow + i);
        if (u.x + u.y + u.z + u.w != 0.0f) {
            if (u.x != 0.0f) sidx[atomicAdd(&scnt, 1)] = IN_PER_SIDE + 4 * i + 0;
            if (u.y != 0.0f) sidx[atomicAdd(&scnt, 1)] = IN_PER_SIDE + 4 * i + 1;
            if (u.z != 0.0f) sidx[atomicAdd(&scnt, 1)] = IN_PER_SIDE + 4 * i + 2;
            if (u.w != 0.0f) sidx[atomicAdd(&scnt, 1)] = IN_PER_SIDE + 4 * i + 3;
        }
    }
    __syncthreads();

    // ---- Phase 2: gather active WTh columns; wave w, lane l.
    const int n = scnt;
    const int w = t >> 6;          // wave 0..7
    const int l = t & 63;          // lane 0..63
    const v8h* WTH8 = (const v8h*)WTh;   // feature f -> WTH8[f*64 + l]

    v8f acc0 = {0,0,0,0,0,0,0,0};
    v8f acc1 = {0,0,0,0,0,0,0,0};
    int k = w;
    for (; k + 16 <= n; k += 16) {
        v8h h0 = WTH8[(size_t)sidx[k]     * 64 + l];
        v8h h1 = WTH8[(size_t)sidx[k + 8] * 64 + l];
        acc0 += __builtin_convertvector(h0, v8f);
        acc1 += __builtin_convertvector(h1, v8f);
    }
    for (; k < n; k += 8)
        acc0 += __builtin_convertvector(WTH8[(size_t)sidx[k] * 64 + l], v8f);
    acc0 += acc1;

    // scalar LDS stores at pad-9 stride: bank = (9*l + i) % 32, 9 odd ->
    // distinct over 32 lanes per i -> conflict-free.
    {
        float* dst = &accs[(w * 64 + l) * 9];
#pragma unroll
        for (int i = 0; i < 8; ++i) dst[i] = acc0[i];
    }
    __syncthreads();

    // ---- reduce waves + bias + clipped ReLU; thread t = neuron t.
    {
        const int ll = t >> 3, c = t & 7;
        float s = 0.0f;
#pragma unroll
        for (int ww = 0; ww < 8; ++ww) s += accs[(ww * 64 + ll) * 9 + c];
        l1s[t] = fminf(fmaxf(s + b_in[t], 0.0f), 1.0f);
    }
    __syncthreads();

    // ---- Phase 3: l2 = clip(l1 @ W1.T + b1): output k owned by 16 lanes
    {
        const int kk = t >> 4;
        const int gg = t & 15;
        const float* wp = W1 + (size_t)kk * L1;
        float p = 0.0f;
        for (int o = gg; o < L1; o += 16) p += wp[o] * l1s[o];
#pragma unroll
        for (int off = 8; off > 0; off >>= 1) p += __shfl_down(p, off, 16);
        if (gg == 0) l2acc[kk] = p;
    }
    __syncthreads();
    if (t < L2) l2s[t] = fminf(fmaxf(l2acc[t] + b1[t], 0.0f), 1.0f);
    __syncthreads();

    // ---- Phase 4: l3 = clip(l2 @ W2.T + b2), 32x32
    if (t < L3_) {
        const float* wp = W2 + (size_t)t * L2;
        float p = b2[t];
#pragma unroll
        for (int q = 0; q < L2; ++q) p += wp[q] * l2s[q];
        l3s[t] = fminf(fmaxf(p, 0.0f), 1.0f);
    }
    __syncthreads();

    // ---- Phase 5: out = l3 @ W3.T + b3
    if (t == 0) {
        float p = b3[0];
#pragma unroll
        for (int q = 0; q < L3_; ++q) p += W3[q] * l3s[q];
        out[b] = p;
    }
}

// ---------------------------------------------------------------------------
// Fallback (ws too small for WTh): fused kernel reading W_in columns
// directly. Correct but slow; not expected to run (ws ~2.5 GiB >> 84 MB).
// ---------------------------------------------------------------------------
__global__ __launch_bounds__(512) void nnue_fallback(
    const float* __restrict__ wf, const float* __restrict__ bfeat,
    const float* __restrict__ W_in, const float* __restrict__ b_in,
    const float* __restrict__ W1, const float* __restrict__ b1,
    const float* __restrict__ W2, const float* __restrict__ b2,
    const float* __restrict__ W3, const float* __restrict__ b3,
    float* __restrict__ out)
{
    const int b = blockIdx.x;
    const int t = threadIdx.x;
    __shared__ int   idxs[MAXIDX];
    __shared__ int   scnt;
    __shared__ float l1s[L1];
    __shared__ float l2acc[L2];
    __shared__ float l2s[L2];
    __shared__ float l3s[L3_];

    if (t == 0) scnt = 0;
    __syncthreads();
    const v4f* wrow = (const v4f*)(wf    + (size_t)b * IN_PER_SIDE);
    const v4f* brow = (const v4f*)(bfeat + (size_t)b * IN_PER_SIDE);
    for (int i = t; i < IN_PER_SIDE / 4; i += 512) {
        v4f v = wrow[i];
        if (v.x != 0.0f) idxs[atomicAdd(&scnt, 1)] = 4 * i + 0;
        if (v.y != 0.0f) idxs[atomicAdd(&scnt, 1)] = 4 * i + 1;
        if (v.z != 0.0f) idxs[atomicAdd(&scnt, 1)] = 4 * i + 2;
        if (v.w != 0.0f) idxs[atomicAdd(&scnt, 1)] = 4 * i + 3;
        v4f u = brow[i];
        if (u.x != 0.0f) idxs[atomicAdd(&scnt, 1)] = IN_PER_SIDE + 4 * i + 0;
        if (u.y != 0.0f) idxs[atomicAdd(&scnt, 1)] = IN_PER_SIDE + 4 * i + 1;
        if (u.z != 0.0f) idxs[atomicAdd(&scnt, 1)] = IN_PER_SIDE + 4 * i + 2;
        if (u.w != 0.0f) idxs[atomicAdd(&scnt, 1)] = IN_PER_SIDE + 4 * i + 3;
    }
    __syncthreads();
    const int n = scnt;
    float a0 = 0.0f;
    const float* row = W_in + (size_t)t * IN_TOTAL;
    for (int i = 0; i < n; ++i) a0 += row[idxs[i]];
    l1s[t] = fminf(fmaxf(b_in[t] + a0, 0.0f), 1.0f);
    __syncthreads();
    {
        const int k = t >> 4, g = t & 15;
        const float* wp = W1 + (size_t)k * L1;
        float p = 0.0f;
        for (int o = g; o < L1; o += 16) p += wp[o] * l1s[o];
#pragma unroll
        for (int off = 8; off > 0; off >>= 1) p += __shfl_down(p, off, 16);
        if (g == 0) l2acc[k] = p;
    }
    __syncthreads();
    if (t < L2) l2s[t] = fminf(fmaxf(l2acc[t] + b1[t], 0.0f), 1.0f);
    __syncthreads();
    if (t < L3_) {
        const float* wp = W2 + (size_t)t * L2;
        float p = b2[t];
#pragma unroll
        for (int q = 0; q < L2; ++q) p += wp[q] * l2s[q];
        l3s[t] = fminf(fmaxf(p, 0.0f), 1.0f);
    }
    __syncthreads();
    if (t == 0) {
        float p = b3[0];
#pragma unroll
        for (int q = 0; q < L3_; ++q) p += W3[q] * l3s[q];
        out[b] = p;
    }
}

extern "C" void kernel_launch(void* const* d_in, const int* in_sizes, int n_in,
                              void* d_out, int out_size, void* d_ws, size_t ws_size,
                              hipStream_t stream) {
    const float* wf   = (const float*)d_in[0];
    const float* bfeat= (const float*)d_in[1];
    const float* W_in = (const float*)d_in[2];
    const float* b_in = (const float*)d_in[3];
    const float* W1   = (const float*)d_in[4];
    const float* b1   = (const float*)d_in[5];
    const float* W2   = (const float*)d_in[6];
    const float* b2   = (const float*)d_in[7];
    const float* W3   = (const float*)d_in[8];
    const float* b3   = (const float*)d_in[9];
    float* out = (float*)d_out;

    if (ws_size >= WT_BYTES) {
        _Float16* WTh = (_Float16*)d_ws;
        dim3 grid(IN_TOTAL / 64, L1 / 64);   // (1280, 8)
        transpose_win<<<grid, 256, 0, stream>>>(W_in, WTh);
        nnue_fused<<<BATCH, 512, 0, stream>>>(
            wf, bfeat, WTh, b_in, W1, b1, W2, b2, W3, b3, out);
    } else {
        nnue_fallback<<<BATCH, 512, 0, stream>>>(
            wf, bfeat, W_in, b_in, W1, b1, W2, b2, W3, b3, out);
    }
}